// Round 1
// baseline (1457.807 us; speedup 1.0000x reference)
//
#include <hip/hip_runtime.h>
#include <hip/hip_bf16.h>
#include <math.h>

// Problem constants
#define BB 4
#define TT 2048
#define HH 1024      // HID == H == P == 1024
#define PP 1024
#define MT 8192      // BB*TT rows
#define C2 2048      // packed re/im columns
#define NC 64        // scan chunks
#define LCH 32       // chunk length (TT/NC)

// ---------------------------------------------------------------------------
// Repack B_param (P,H,2) -> Bpk (2P, H): row p = B_re[p,:], row P+p = B_im[p,:]
__global__ void repack_B_kernel(const float* __restrict__ src, float* __restrict__ dst) {
    int idx = blockIdx.x * 256 + threadIdx.x;     // 0 .. 1024*1024-1
    int p = idx >> 10;
    int h = idx & 1023;
    float2 v = *(const float2*)(src + ((size_t)p << 11) + (h << 1));
    dst[(size_t)p * HH + h]            = v.x;
    dst[(size_t)(p + PP) * HH + h]     = v.y;
}

// Repack C_param (H,P,2) -> Cpk (H, 2P): col p = C_re[h,p], col P+p = -C_im[h,p]
__global__ void repack_C_kernel(const float* __restrict__ src, float* __restrict__ dst) {
    int idx = blockIdx.x * 256 + threadIdx.x;     // 0 .. 1024*1024-1
    int h = idx >> 10;
    int p = idx & 1023;
    float2 v = *(const float2*)(src + ((size_t)h << 11) + (p << 1));
    dst[(size_t)h * C2 + p]       = v.x;
    dst[(size_t)h * C2 + PP + p]  = -v.y;
}

// ---------------------------------------------------------------------------
// fp32 NT GEMM: C[m,n] = sum_k A[m*lda+k] * B[n*ldb+k]
// 128x128 tile, BK=16, 256 threads, 8x8 microtile (split 4+4 for LDS bcast).
#define GBM 128
#define GBN 128
#define GBK 16
__global__ __launch_bounds__(256) void gemm_nt(
    const float* __restrict__ A, int lda,
    const float* __restrict__ B, int ldb,
    float* __restrict__ C, int ldc, int K)
{
    __shared__ float As[GBK][GBM + 4];
    __shared__ float Bs[GBK][GBN + 4];
    const int bm = blockIdx.y * GBM;
    const int bn = blockIdx.x * GBN;
    const int tid = threadIdx.x;
    const int tx = tid & 15;
    const int ty = tid >> 4;

    float acc[8][8];
#pragma unroll
    for (int i = 0; i < 8; ++i)
#pragma unroll
        for (int j = 0; j < 8; ++j) acc[i][j] = 0.f;

    for (int k0 = 0; k0 < K; k0 += GBK) {
#pragma unroll
        for (int l = 0; l < 2; ++l) {
            int e  = tid + l * 256;
            int r  = e >> 2;
            int c4 = (e & 3) << 2;
            float4 va = *(const float4*)(A + (size_t)(bm + r) * lda + k0 + c4);
            As[c4 + 0][r] = va.x; As[c4 + 1][r] = va.y;
            As[c4 + 2][r] = va.z; As[c4 + 3][r] = va.w;
            float4 vb = *(const float4*)(B + (size_t)(bn + r) * ldb + k0 + c4);
            Bs[c4 + 0][r] = vb.x; Bs[c4 + 1][r] = vb.y;
            Bs[c4 + 2][r] = vb.z; Bs[c4 + 3][r] = vb.w;
        }
        __syncthreads();
#pragma unroll
        for (int k = 0; k < GBK; ++k) {
            float a[8], b[8];
            *(float4*)&a[0] = *(const float4*)&As[k][ty << 2];
            *(float4*)&a[4] = *(const float4*)&As[k][64 + (ty << 2)];
            *(float4*)&b[0] = *(const float4*)&Bs[k][tx << 2];
            *(float4*)&b[4] = *(const float4*)&Bs[k][64 + (tx << 2)];
#pragma unroll
            for (int i = 0; i < 8; ++i)
#pragma unroll
                for (int j = 0; j < 8; ++j)
                    acc[i][j] = fmaf(a[i], b[j], acc[i][j]);
        }
        __syncthreads();
    }

#pragma unroll
    for (int ih = 0; ih < 2; ++ih) {
#pragma unroll
        for (int ii = 0; ii < 4; ++ii) {
            int i = ih * 4 + ii;
            int row = bm + ih * 64 + (ty << 2) + ii;
            float4 v0 = make_float4(acc[i][0], acc[i][1], acc[i][2], acc[i][3]);
            float4 v1 = make_float4(acc[i][4], acc[i][5], acc[i][6], acc[i][7]);
            *(float4*)(C + (size_t)row * ldc + bn + (tx << 2))      = v0;
            *(float4*)(C + (size_t)row * ldc + bn + 64 + (tx << 2)) = v1;
        }
    }
}

// ---------------------------------------------------------------------------
// Scan helpers: per column c (0..2047), p = c & 1023; IM discretization.
__device__ __forceinline__ void linoss_coeffs(const float* A_diag, const float* dt_p,
                                              int p, float& m11, float& m12,
                                              float& m21, float& m22,
                                              float& f1, float& f2) {
    float A  = fmaxf(A_diag[p], 0.f);
    float dt = 1.f / (1.f + expf(-dt_p[p]));
    float S  = 1.f / (1.f + dt * dt * A);
    m11 = S;        m12 = -dt * A * S;
    m21 = dt * S;   m22 = S;
    f1  = dt * S;   f2  = dt * dt * S;
}

// Pass A: per (c, b, chunk j) thread, scan chunk from zero state -> local end.
__global__ void scan_passA(const float* __restrict__ Bu,
                           const float* __restrict__ A_diag,
                           const float* __restrict__ dt_p,
                           float2* __restrict__ sEnd) {
    int c = blockIdx.x * 256 + threadIdx.x;  // 0..2047
    int b = blockIdx.y;
    int j = blockIdx.z;
    float m11, m12, m21, m22, f1, f2;
    linoss_coeffs(A_diag, dt_p, c & 1023, m11, m12, m21, m22, f1, f2);
    const float* bu = Bu + ((size_t)(b * TT + j * LCH)) * C2 + c;
    float z = 0.f, y = 0.f;
#pragma unroll 8
    for (int i = 0; i < LCH; ++i) {
        float u  = bu[(size_t)i * C2];
        float z1 = m11 * z + m12 * y + f1 * u;
        float y1 = m21 * z + m22 * y + f2 * u;
        z = z1; y = y1;
    }
    sEnd[((size_t)j * BB + b) * C2 + c] = make_float2(z, y);
}

// Combine: per (b,c) channel, serial over NC chunks with M^LCH jumps.
__global__ void scan_combine(const float* __restrict__ A_diag,
                             const float* __restrict__ dt_p,
                             const float2* __restrict__ sEnd,
                             float2* __restrict__ sInit) {
    int idx = blockIdx.x * 256 + threadIdx.x;   // 0..8191
    int c = idx & (C2 - 1);
    int b = idx >> 11;
    float m11, m12, m21, m22, f1, f2;
    linoss_coeffs(A_diag, dt_p, c & 1023, m11, m12, m21, m22, f1, f2);
    // e = M^32 via 5 squarings
    float e11 = m11, e12 = m12, e21 = m21, e22 = m22;
#pragma unroll
    for (int s = 0; s < 5; ++s) {
        float n11 = e11 * e11 + e12 * e21;
        float n12 = e11 * e12 + e12 * e22;
        float n21 = e21 * e11 + e22 * e21;
        float n22 = e21 * e12 + e22 * e22;
        e11 = n11; e12 = n12; e21 = n21; e22 = n22;
    }
    float z = 0.f, y = 0.f;
    for (int j = 0; j < NC; ++j) {
        size_t off = ((size_t)j * BB + b) * C2 + c;
        sInit[off] = make_float2(z, y);
        float2 le = sEnd[off];
        float z1 = e11 * z + e12 * y + le.x;
        float y1 = e21 * z + e22 * y + le.y;
        z = z1; y = y1;
    }
}

// Pass B: rescan each chunk from its correct initial state, emit y into YS.
__global__ void scan_passB(const float* __restrict__ Bu,
                           const float* __restrict__ A_diag,
                           const float* __restrict__ dt_p,
                           const float2* __restrict__ sInit,
                           float* __restrict__ YS) {
    int c = blockIdx.x * 256 + threadIdx.x;
    int b = blockIdx.y;
    int j = blockIdx.z;
    float m11, m12, m21, m22, f1, f2;
    linoss_coeffs(A_diag, dt_p, c & 1023, m11, m12, m21, m22, f1, f2);
    float2 s0 = sInit[((size_t)j * BB + b) * C2 + c];
    float z = s0.x, y = s0.y;
    const float* bu = Bu + ((size_t)(b * TT + j * LCH)) * C2 + c;
    float*       ys = YS + ((size_t)(b * TT + j * LCH)) * C2 + c;
#pragma unroll 8
    for (int i = 0; i < LCH; ++i) {
        float u  = bu[(size_t)i * C2];
        float z1 = m11 * z + m12 * y + f1 * u;
        float y1 = m21 * z + m22 * y + f2 * u;
        z = z1; y = y1;
        ys[(size_t)i * C2] = y;
    }
}

// ---------------------------------------------------------------------------
// Fused epilogue: o = O + D*x ; rms = rsqrt(mean(o^2)+eps) ;
// v = o*rms*nw * (g*sigmoid(g)).  One block (256 thr) per row (4 h each).
__global__ void rmsgate_kernel(const float* __restrict__ O,
                               const float* __restrict__ XG,
                               const float* __restrict__ Dv,
                               const float* __restrict__ nw,
                               float* __restrict__ V) {
    int m = blockIdx.x;
    int t = threadIdx.x;
    float4 o4 = *(const float4*)(O  + (size_t)m * HH + (t << 2));
    float4 x4 = *(const float4*)(XG + (size_t)m * C2 + (t << 2));
    float4 d4 = *(const float4*)(Dv + (t << 2));
    float of[4];
    of[0] = o4.x + d4.x * x4.x;
    of[1] = o4.y + d4.y * x4.y;
    of[2] = o4.z + d4.z * x4.z;
    of[3] = o4.w + d4.w * x4.w;
    float ss = of[0]*of[0] + of[1]*of[1] + of[2]*of[2] + of[3]*of[3];
#pragma unroll
    for (int o = 32; o > 0; o >>= 1) ss += __shfl_down(ss, o);
    __shared__ float wsum[4];
    if ((t & 63) == 0) wsum[t >> 6] = ss;
    __syncthreads();
    float tot = wsum[0] + wsum[1] + wsum[2] + wsum[3];
    float r = rsqrtf(tot * (1.f / (float)HH) + 1e-5f);

    float4 g4 = *(const float4*)(XG + (size_t)m * C2 + HH + (t << 2));
    float4 w4 = *(const float4*)(nw + (t << 2));
    float g[4] = {g4.x, g4.y, g4.z, g4.w};
    float w[4] = {w4.x, w4.y, w4.z, w4.w};
    float4 vout;
    float* vo = &vout.x;
#pragma unroll
    for (int i = 0; i < 4; ++i) {
        float sw = g[i] / (1.f + expf(-g[i]));
        vo[i] = of[i] * r * w[i] * sw;
    }
    *(float4*)(V + (size_t)m * HH + (t << 2)) = vout;
}

// ---------------------------------------------------------------------------
extern "C" void kernel_launch(void* const* d_in, const int* in_sizes, int n_in,
                              void* d_out, int out_size, void* d_ws, size_t ws_size,
                              hipStream_t stream) {
    const float* hs      = (const float*)d_in[0];   // (4,2048,1024)
    const float* Wi      = (const float*)d_in[1];   // (1024,1024)
    const float* Wg      = (const float*)d_in[2];   // (1024,1024)
    const float* Wo      = (const float*)d_in[3];   // (1024,1024)
    const float* A_diag  = (const float*)d_in[4];   // (1024,)
    const float* B_param = (const float*)d_in[5];   // (1024,1024,2)
    const float* C_param = (const float*)d_in[6];   // (1024,1024,2)
    const float* Dv      = (const float*)d_in[7];   // (1024,)
    const float* dtp     = (const float*)d_in[8];   // (1024,)
    const float* nw      = (const float*)d_in[9];   // (1024,)
    float* out = (float*)d_out;

    float* ws = (float*)d_ws;
    float* XG  = ws;                         // 8192*2048: cols [0,1024)=x, [1024,2048)=g
    float* Bu  = XG + (size_t)MT * C2;       // 8192*2048: cols p=re, 1024+p=im
    float* YS  = Bu + (size_t)MT * C2;       // 8192*2048
    float* Bpk = YS + (size_t)MT * C2;       // 2048*1024
    float* Cpk = Bpk + (size_t)C2 * HH;      // 1024*2048
    float2* sEnd  = (float2*)(Cpk + (size_t)HH * C2);  // 64*4*2048
    float2* sInit = sEnd + (size_t)NC * BB * C2;
    float* O = Bu;                           // reuse Bu (dead after passB): 8192*1024
    float* V = Bu + (size_t)MT * HH;         // reuse: 8192*1024

    dim3 blk(256);

    repack_B_kernel<<<dim3((PP * HH) / 256), blk, 0, stream>>>(B_param, Bpk);
    repack_C_kernel<<<dim3((HH * PP) / 256), blk, 0, stream>>>(C_param, Cpk);

    // x = hs @ Wi^T ; g = hs @ Wg^T   (into XG halves)
    gemm_nt<<<dim3(HH / GBN, MT / GBM), blk, 0, stream>>>(hs, HH, Wi, HH, XG, C2, HH);
    gemm_nt<<<dim3(HH / GBN, MT / GBM), blk, 0, stream>>>(hs, HH, Wg, HH, XG + HH, C2, HH);

    // Bu = x @ Bpk^T  (N = 2048 covers re|im)
    gemm_nt<<<dim3(C2 / GBN, MT / GBM), blk, 0, stream>>>(XG, C2, Bpk, HH, Bu, C2, HH);

    // chunked linear scan
    scan_passA<<<dim3(C2 / 256, BB, NC), blk, 0, stream>>>(Bu, A_diag, dtp, sEnd);
    scan_combine<<<dim3((BB * C2) / 256), blk, 0, stream>>>(A_diag, dtp, sEnd, sInit);
    scan_passB<<<dim3(C2 / 256, BB, NC), blk, 0, stream>>>(Bu, A_diag, dtp, sInit, YS);

    // O = YS @ Cpk^T  (K = 2048 covers re - im)
    gemm_nt<<<dim3(HH / GBN, MT / GBM), blk, 0, stream>>>(YS, C2, Cpk, C2, O, HH, C2);

    // fused D*x + RMSNorm + swish gate
    rmsgate_kernel<<<dim3(MT), blk, 0, stream>>>(O, XG, Dv, nw, V);

    // out = V @ Wo^T
    gemm_nt<<<dim3(HH / GBN, MT / GBM), blk, 0, stream>>>(V, HH, Wo, HH, out, HH, HH);
}

// Round 2
// 280.443 us; speedup vs baseline: 5.1982x; 5.1982x over previous
//
#include <hip/hip_runtime.h>
#include <hip/hip_bf16.h>
#include <math.h>

// Problem constants
#define BB 4
#define TT 2048
#define HH 1024      // HID == H == P == 1024
#define PP 1024
#define MT 8192      // BB*TT rows
#define C2 2048      // packed re/im columns
#define NC 64        // scan chunks
#define LCH 32       // chunk length (TT/NC)

typedef __attribute__((ext_vector_type(8))) short  bf16x8;
typedef __attribute__((ext_vector_type(4))) float  f32x4;

__device__ __forceinline__ ushort f2bf(float f) {
    union { float f; unsigned u; } v; v.f = f;
    unsigned r = v.u + 0x7fffu + ((v.u >> 16) & 1u);   // RNE
    return (ushort)(r >> 16);
}
__device__ __forceinline__ float bf2f(ushort h) {
    union { unsigned u; float f; } v; v.u = ((unsigned)h) << 16;
    return v.f;
}

// async global -> LDS, 16B per lane (dest = wave-uniform base + lane*16)
__device__ __forceinline__ void gload16(const ushort* g, ushort* l) {
    __builtin_amdgcn_global_load_lds((const __attribute__((address_space(1))) void*)g,
                                     (__attribute__((address_space(3))) void*)l,
                                     16, 0, 0);
}

// ---------------------------------------------------------------------------
// fp32 -> bf16 bulk convert (4 elems/thread)
__global__ void f32_to_bf16_k(const float* __restrict__ s, ushort* __restrict__ d) {
    int i = blockIdx.x * 256 + threadIdx.x;
    float4 v = ((const float4*)s)[i];
    ushort4 o;
    o.x = f2bf(v.x); o.y = f2bf(v.y); o.z = f2bf(v.z); o.w = f2bf(v.w);
    ((ushort4*)d)[i] = o;
}

// B_param (P,H,2) -> Bpk (2P,H) bf16: row p = re, row P+p = im
__global__ void repack_B_bf(const float* __restrict__ src, ushort* __restrict__ dst) {
    int idx = blockIdx.x * 256 + threadIdx.x;   // 0 .. 1M-1
    int p = idx >> 10;
    int h = idx & 1023;
    float2 v = ((const float2*)src)[idx];
    dst[(size_t)p * HH + h]        = f2bf(v.x);
    dst[(size_t)(p + PP) * HH + h] = f2bf(v.y);
}

// C_param (H,P,2) -> Cpk (H,2P) bf16: col p = re, col P+p = -im
__global__ void repack_C_bf(const float* __restrict__ src, ushort* __restrict__ dst) {
    int idx = blockIdx.x * 256 + threadIdx.x;
    int h = idx >> 10;
    int p = idx & 1023;
    float2 v = ((const float2*)src)[idx];
    dst[(size_t)h * C2 + p]      = f2bf(v.x);
    dst[(size_t)h * C2 + PP + p] = f2bf(-v.y);
}

// ---------------------------------------------------------------------------
// bf16 MFMA NT GEMM (m97 structure): C[m,n] = sum_k A[m,k]*B[n,k]
// 128x128 tile, BK=32, 256 thr = 4 waves (2x2), 64x64 per wave,
// 16x16x32 MFMA, global_load_lds width-16 staging, single LDS buffer.
template<int STORE_BF16>
__global__ __launch_bounds__(256) void gemm_bf16_nt(
    const ushort* __restrict__ A, int lda,
    const ushort* __restrict__ B, int ldb,
    void* __restrict__ Cptr, int ldc, int K)
{
    __shared__ __align__(16) ushort As[128 * 32];
    __shared__ __align__(16) ushort Bs[128 * 32];
    const int tid  = threadIdx.x;
    const int wave = tid >> 6;
    const int lane = tid & 63;
    const int bm = blockIdx.y * 128;
    const int bn = blockIdx.x * 128;
    const int wr = (wave >> 1) * 64;
    const int wc = (wave & 1) * 64;

    // staging: lane covers row (tid>>2), k-bytes (tid&3)*16; call1 = rows+64
    const int srow = tid >> 2;
    const int scol = (tid & 3) * 8;
    const ushort* ag = A + (size_t)(bm + srow) * lda + scol;
    const ushort* bg = B + (size_t)(bn + srow) * ldb + scol;
    ushort* al0 = As + wave * 512;   // wave-uniform LDS base (1KB per wave)
    ushort* bl0 = Bs + wave * 512;

    const int lr = lane & 15;
    const int kg = lane >> 4;

    f32x4 acc[4][4];
#pragma unroll
    for (int f = 0; f < 4; ++f)
#pragma unroll
        for (int g = 0; g < 4; ++g)
#pragma unroll
            for (int i = 0; i < 4; ++i) acc[f][g][i] = 0.f;

    for (int k0 = 0; k0 < K; k0 += 32) {
        gload16(ag + k0,                     al0);
        gload16(ag + k0 + (size_t)64 * lda,  al0 + 2048);
        gload16(bg + k0,                     bl0);
        gload16(bg + k0 + (size_t)64 * ldb,  bl0 + 2048);
        __syncthreads();   // drains vmcnt -> staged tile visible

        bf16x8 af[4], bf[4];
#pragma unroll
        for (int f = 0; f < 4; ++f)
            af[f] = *(const bf16x8*)&As[(wr + f * 16 + lr) * 32 + kg * 8];
#pragma unroll
        for (int g = 0; g < 4; ++g)
            bf[g] = *(const bf16x8*)&Bs[(wc + g * 16 + lr) * 32 + kg * 8];
#pragma unroll
        for (int f = 0; f < 4; ++f)
#pragma unroll
            for (int g = 0; g < 4; ++g)
                acc[f][g] = __builtin_amdgcn_mfma_f32_16x16x32_bf16(
                    af[f], bf[g], acc[f][g], 0, 0, 0);
        __syncthreads();
    }

    // epilogue: D row = (lane>>4)*4 + reg, col = lane&15  [m89/m91 verified]
#pragma unroll
    for (int f = 0; f < 4; ++f) {
#pragma unroll
        for (int g = 0; g < 4; ++g) {
            int col = bn + wc + g * 16 + lr;
#pragma unroll
            for (int i = 0; i < 4; ++i) {
                int row = bm + wr + f * 16 + kg * 4 + i;
                float v = acc[f][g][i];
                if (STORE_BF16)
                    ((ushort*)Cptr)[(size_t)row * ldc + col] = f2bf(v);
                else
                    ((float*)Cptr)[(size_t)row * ldc + col] = v;
            }
        }
    }
}

// ---------------------------------------------------------------------------
// Scan (fp32, IM discretization), chunk-parallel: passA -> combine -> passB
__device__ __forceinline__ void linoss_coeffs(const float* A_diag, const float* dt_p,
                                              int p, float& m11, float& m12,
                                              float& m21, float& m22,
                                              float& f1, float& f2) {
    float A  = fmaxf(A_diag[p], 0.f);
    float dt = 1.f / (1.f + expf(-dt_p[p]));
    float S  = 1.f / (1.f + dt * dt * A);
    m11 = S;        m12 = -dt * A * S;
    m21 = dt * S;   m22 = S;
    f1  = dt * S;   f2  = dt * dt * S;
}

__global__ void scan_passA(const float* __restrict__ Bu,
                           const float* __restrict__ A_diag,
                           const float* __restrict__ dt_p,
                           float2* __restrict__ sEnd) {
    int c = blockIdx.x * 256 + threadIdx.x;
    int b = blockIdx.y;
    int j = blockIdx.z;
    float m11, m12, m21, m22, f1, f2;
    linoss_coeffs(A_diag, dt_p, c & 1023, m11, m12, m21, m22, f1, f2);
    const float* bu = Bu + ((size_t)(b * TT + j * LCH)) * C2 + c;
    float z = 0.f, y = 0.f;
#pragma unroll 8
    for (int i = 0; i < LCH; ++i) {
        float u  = bu[(size_t)i * C2];
        float z1 = m11 * z + m12 * y + f1 * u;
        float y1 = m21 * z + m22 * y + f2 * u;
        z = z1; y = y1;
    }
    sEnd[((size_t)j * BB + b) * C2 + c] = make_float2(z, y);
}

__global__ void scan_combine(const float* __restrict__ A_diag,
                             const float* __restrict__ dt_p,
                             const float2* __restrict__ sEnd,
                             float2* __restrict__ sInit) {
    int idx = blockIdx.x * 256 + threadIdx.x;   // 0..8191
    int c = idx & (C2 - 1);
    int b = idx >> 11;
    float m11, m12, m21, m22, f1, f2;
    linoss_coeffs(A_diag, dt_p, c & 1023, m11, m12, m21, m22, f1, f2);
    float e11 = m11, e12 = m12, e21 = m21, e22 = m22;   // M^32 by 5 squarings
#pragma unroll
    for (int s = 0; s < 5; ++s) {
        float n11 = e11 * e11 + e12 * e21;
        float n12 = e11 * e12 + e12 * e22;
        float n21 = e21 * e11 + e22 * e21;
        float n22 = e21 * e12 + e22 * e22;
        e11 = n11; e12 = n12; e21 = n21; e22 = n22;
    }
    float z = 0.f, y = 0.f;
    for (int j = 0; j < NC; ++j) {
        size_t off = ((size_t)j * BB + b) * C2 + c;
        sInit[off] = make_float2(z, y);
        float2 le = sEnd[off];
        float z1 = e11 * z + e12 * y + le.x;
        float y1 = e21 * z + e22 * y + le.y;
        z = z1; y = y1;
    }
}

// passB rescans from correct initial state, emits y as bf16 into YSb
__global__ void scan_passB(const float* __restrict__ Bu,
                           const float* __restrict__ A_diag,
                           const float* __restrict__ dt_p,
                           const float2* __restrict__ sInit,
                           ushort* __restrict__ YSb) {
    int c = blockIdx.x * 256 + threadIdx.x;
    int b = blockIdx.y;
    int j = blockIdx.z;
    float m11, m12, m21, m22, f1, f2;
    linoss_coeffs(A_diag, dt_p, c & 1023, m11, m12, m21, m22, f1, f2);
    float2 s0 = sInit[((size_t)j * BB + b) * C2 + c];
    float z = s0.x, y = s0.y;
    const float* bu = Bu  + ((size_t)(b * TT + j * LCH)) * C2 + c;
    ushort*      ys = YSb + ((size_t)(b * TT + j * LCH)) * C2 + c;
#pragma unroll 8
    for (int i = 0; i < LCH; ++i) {
        float u  = bu[(size_t)i * C2];
        float z1 = m11 * z + m12 * y + f1 * u;
        float y1 = m21 * z + m22 * y + f2 * u;
        z = z1; y = y1;
        ys[(size_t)i * C2] = f2bf(y);
    }
}

// ---------------------------------------------------------------------------
// Fused epilogue: o = O + D*x ; rms-normalize ; * nw * swish(g) -> V (bf16)
__global__ void rmsgate_kernel(const float* __restrict__ O,
                               const ushort* __restrict__ XGb,
                               const float* __restrict__ Dv,
                               const float* __restrict__ nw,
                               ushort* __restrict__ V) {
    int m = blockIdx.x;
    int t = threadIdx.x;
    float4  o4 = ((const float4*)(O + (size_t)m * HH))[t];
    ushort4 x4 = ((const ushort4*)(XGb + (size_t)m * C2))[t];
    float4  d4 = ((const float4*)Dv)[t];
    float of[4];
    of[0] = o4.x + d4.x * bf2f(x4.x);
    of[1] = o4.y + d4.y * bf2f(x4.y);
    of[2] = o4.z + d4.z * bf2f(x4.z);
    of[3] = o4.w + d4.w * bf2f(x4.w);
    float ss = of[0]*of[0] + of[1]*of[1] + of[2]*of[2] + of[3]*of[3];
#pragma unroll
    for (int o = 32; o > 0; o >>= 1) ss += __shfl_down(ss, o);
    __shared__ float wsum[4];
    if ((t & 63) == 0) wsum[t >> 6] = ss;
    __syncthreads();
    float tot = wsum[0] + wsum[1] + wsum[2] + wsum[3];
    float r = rsqrtf(tot * (1.f / (float)HH) + 1e-5f);

    ushort4 g4 = ((const ushort4*)(XGb + (size_t)m * C2 + HH))[t];
    float4  w4 = ((const float4*)nw)[t];
    float g[4] = {bf2f(g4.x), bf2f(g4.y), bf2f(g4.z), bf2f(g4.w)};
    float w[4] = {w4.x, w4.y, w4.z, w4.w};
    ushort4 vout;
    ushort* vo = &vout.x;
#pragma unroll
    for (int i = 0; i < 4; ++i) {
        float sw = g[i] / (1.f + expf(-g[i]));
        vo[i] = f2bf(of[i] * r * w[i] * sw);
    }
    ((ushort4*)(V + (size_t)m * HH))[t] = vout;
}

// ---------------------------------------------------------------------------
extern "C" void kernel_launch(void* const* d_in, const int* in_sizes, int n_in,
                              void* d_out, int out_size, void* d_ws, size_t ws_size,
                              hipStream_t stream) {
    const float* hs      = (const float*)d_in[0];
    const float* Wi      = (const float*)d_in[1];
    const float* Wg      = (const float*)d_in[2];
    const float* Wo      = (const float*)d_in[3];
    const float* A_diag  = (const float*)d_in[4];
    const float* B_param = (const float*)d_in[5];
    const float* C_param = (const float*)d_in[6];
    const float* Dv      = (const float*)d_in[7];
    const float* dtp     = (const float*)d_in[8];
    const float* nw      = (const float*)d_in[9];
    float* out = (float*)d_out;

    char* ws = (char*)d_ws;
    ushort* hsb  = (ushort*)ws;                                   ws += (size_t)MT * HH * 2;   // 16 MB
    ushort* Wigb = (ushort*)ws;                                   ws += (size_t)C2 * HH * 2;   //  4 MB
    ushort* Wob  = (ushort*)ws;                                   ws += (size_t)HH * HH * 2;   //  2 MB
    ushort* Bpkb = (ushort*)ws;                                   ws += (size_t)C2 * HH * 2;   //  4 MB
    ushort* Cpkb = (ushort*)ws;                                   ws += (size_t)HH * C2 * 2;   //  4 MB
    ushort* XGb  = (ushort*)ws;                                   ws += (size_t)MT * C2 * 2;   // 32 MB
    float*  Bu   = (float*)ws;                                    ws += (size_t)MT * C2 * 4;   // 64 MB
    ushort* YSb  = (ushort*)ws;                                   ws += (size_t)MT * C2 * 2;   // 32 MB
    float*  O    = (float*)ws;                                    ws += (size_t)MT * HH * 4;   // 32 MB
    ushort* Vb   = (ushort*)ws;                                   ws += (size_t)MT * HH * 2;   // 16 MB
    float2* sEnd  = (float2*)ws;                                  ws += (size_t)NC * BB * C2 * 8;
    float2* sInit = (float2*)ws;

    dim3 blk(256);

    // convert / repack params and activations to bf16
    f32_to_bf16_k<<<dim3((MT * HH) / 1024), blk, 0, stream>>>(hs, hsb);
    f32_to_bf16_k<<<dim3((HH * HH) / 1024), blk, 0, stream>>>(Wi, Wigb);
    f32_to_bf16_k<<<dim3((HH * HH) / 1024), blk, 0, stream>>>(Wg, Wigb + (size_t)HH * HH);
    f32_to_bf16_k<<<dim3((HH * HH) / 1024), blk, 0, stream>>>(Wo, Wob);
    repack_B_bf<<<dim3((PP * HH) / 256), blk, 0, stream>>>(B_param, Bpkb);
    repack_C_bf<<<dim3((HH * PP) / 256), blk, 0, stream>>>(C_param, Cpkb);

    // XG = hs @ [Wi|Wg]^T   (M=8192, N=2048, K=1024) -> bf16
    gemm_bf16_nt<1><<<dim3(C2 / 128, MT / 128), blk, 0, stream>>>(
        hsb, HH, Wigb, HH, XGb, C2, HH);

    // Bu = x @ Bpk^T        (M=8192, N=2048, K=1024) -> fp32
    gemm_bf16_nt<0><<<dim3(C2 / 128, MT / 128), blk, 0, stream>>>(
        XGb, C2, Bpkb, HH, Bu, C2, HH);

    // chunked linear scan (fp32), YS emitted as bf16
    scan_passA<<<dim3(C2 / 256, BB, NC), blk, 0, stream>>>(Bu, A_diag, dtp, sEnd);
    scan_combine<<<dim3((BB * C2) / 256), blk, 0, stream>>>(A_diag, dtp, sEnd, sInit);
    scan_passB<<<dim3(C2 / 256, BB, NC), blk, 0, stream>>>(Bu, A_diag, dtp, sInit, YSb);

    // O = YS @ Cpk^T        (M=8192, N=1024, K=2048) -> fp32
    gemm_bf16_nt<0><<<dim3(HH / 128, MT / 128), blk, 0, stream>>>(
        YSb, C2, Cpkb, C2, O, HH, C2);

    // fused D*x + RMSNorm + swish gate -> V (bf16)
    rmsgate_kernel<<<dim3(MT), blk, 0, stream>>>(O, XGb, Dv, nw, Vb);

    // out = V @ Wo^T        (M=8192, N=1024, K=1024) -> fp32
    gemm_bf16_nt<0><<<dim3(HH / 128, MT / 128), blk, 0, stream>>>(
        Vb, HH, Wob, HH, out, HH, HH);
}

// Round 3
// 229.210 us; speedup vs baseline: 6.3601x; 1.2235x over previous
//
#include <hip/hip_runtime.h>
#include <hip/hip_bf16.h>
#include <math.h>

// Problem constants
#define BB 4
#define TT 2048
#define HH 1024      // HID == H == P == 1024
#define PP 1024
#define MT 8192      // BB*TT rows
#define C2 2048      // packed re/im columns
#define NC 64        // scan chunks
#define LCH 32       // chunk length (TT/NC)

typedef __attribute__((ext_vector_type(8))) short  bf16x8;
typedef __attribute__((ext_vector_type(4))) float  f32x4;

__device__ __forceinline__ ushort f2bf(float f) {
    union { float f; unsigned u; } v; v.f = f;
    unsigned r = v.u + 0x7fffu + ((v.u >> 16) & 1u);   // RNE
    return (ushort)(r >> 16);
}
__device__ __forceinline__ float bf2f(ushort h) {
    union { unsigned u; float f; } v; v.u = ((unsigned)h) << 16;
    return v.f;
}

// async global -> LDS, 16B per lane (dest = wave-uniform base + lane*16)
__device__ __forceinline__ void gload16(const ushort* g, ushort* l) {
    __builtin_amdgcn_global_load_lds((const __attribute__((address_space(1))) void*)g,
                                     (__attribute__((address_space(3))) void*)l,
                                     16, 0, 0);
}

__device__ __forceinline__ void barrier_raw() { __builtin_amdgcn_s_barrier(); }
__device__ __forceinline__ void lgk0() { asm volatile("s_waitcnt lgkmcnt(0)" ::: "memory"); }
__device__ __forceinline__ void vm6()  { asm volatile("s_waitcnt vmcnt(6)"   ::: "memory"); }
__device__ __forceinline__ void vm0()  { asm volatile("s_waitcnt vmcnt(0)"   ::: "memory"); }

// ---------------------------------------------------------------------------
// fp32 -> bf16 bulk convert (4 elems/thread)
__global__ void f32_to_bf16_k(const float* __restrict__ s, ushort* __restrict__ d) {
    int i = blockIdx.x * 256 + threadIdx.x;
    float4 v = ((const float4*)s)[i];
    ushort4 o;
    o.x = f2bf(v.x); o.y = f2bf(v.y); o.z = f2bf(v.z); o.w = f2bf(v.w);
    ((ushort4*)d)[i] = o;
}

// B_param (P,H,2) -> Bpk (2P,H) bf16: row p = re, row P+p = im
__global__ void repack_B_bf(const float* __restrict__ src, ushort* __restrict__ dst) {
    int idx = blockIdx.x * 256 + threadIdx.x;   // 0 .. 1M-1
    int p = idx >> 10;
    int h = idx & 1023;
    float2 v = ((const float2*)src)[idx];
    dst[(size_t)p * HH + h]        = f2bf(v.x);
    dst[(size_t)(p + PP) * HH + h] = f2bf(v.y);
}

// C_param (H,P,2) -> Cpk (H,2P) bf16: col p = re, col P+p = -im
__global__ void repack_C_bf(const float* __restrict__ src, ushort* __restrict__ dst) {
    int idx = blockIdx.x * 256 + threadIdx.x;
    int h = idx >> 10;
    int p = idx & 1023;
    float2 v = ((const float2*)src)[idx];
    dst[(size_t)h * C2 + p]      = f2bf(v.x);
    dst[(size_t)h * C2 + PP + p] = f2bf(-v.y);
}

// ---------------------------------------------------------------------------
// 8-phase 256-wide bf16 MFMA NT GEMM (T2+T3+T4+T5 stack, BN=256 fixed).
// BM in {256,128}. 512 thr = 8 waves (2Mx4N), per-wave (BM/2)x64 output.
// BK=64, 2 K-tiles per iteration, double-buffered LDS, st_16x32 swizzle,
// counted vmcnt(6) at phases 4/8, raw s_barrier (no vmcnt(0) drain).
template<int BM, int STORE_BF16>
__global__ __launch_bounds__(512, 2) void gemm8p(
    const ushort* __restrict__ A, int lda,
    const ushort* __restrict__ B, int ldb,
    void* __restrict__ Cp, int ldc, int K, int nbx)
{
    constexpr int BN  = 256;
    constexpr int MR  = BM / 32;          // per-wave M fragments (8 or 4)
    constexpr int MRH = MR / 2;           // per qm half (4 or 2)
    constexpr int TA  = BM * 128;         // A tile bytes (32K or 16K)
    constexpr int TB  = BN * 128;         // 32K
    __shared__ __align__(16) char smem[2 * TA + 2 * TB];

    // bijective XCD swizzle (nwg == 256, divisible by 8)
    const int bid = blockIdx.x;
    const int cpx = gridDim.x >> 3;
    const int wg  = (bid & 7) * cpx + (bid >> 3);
    const int by  = wg / nbx;
    const int bx  = wg - by * nbx;
    const int bm  = by * BM;
    const int bn  = bx * BN;

    const int tid  = threadIdx.x;
    const int wave = tid >> 6;
    const int lane = tid & 63;
    const int wr   = wave >> 2;       // 0..1
    const int wc   = wave & 3;        // 0..3
    const int lr   = lane & 15;
    const int kg   = lane >> 4;

    // staging source geometry: LDS linear dest d = u*8192 + wave*1024 + lane*16,
    // content convention lds[d] = element(swz(d)); swz(o)=o^(((o>>9)&1)<<5).
    // bit9 of d == bit5 of lane -> pre-swizzled per-lane source row/col:
    const int e  = (wave << 10) + ((lane << 4) ^ (((lane >> 5) & 1) << 5));
    const int r0 = e >> 7;            // row within 64-row unit
    const int c0 = (e & 127) >> 1;    // col (elements, multiple of 8)

    auto stA = [&](int bi, int u, int kt) {
        gload16(A + (size_t)(bm + u * 64 + r0) * lda + kt * 64 + c0,
                (ushort*)(smem + bi * TA + u * 8192 + (wave << 10)));
    };
    auto stB = [&](int bi, int u, int kt) {
        gload16(B + (size_t)(bn + u * 64 + r0) * ldb + kt * 64 + c0,
                (ushort*)(smem + 2 * TA + bi * TB + u * 8192 + (wave << 10)));
    };

    bf16x8 Af[MRH][2], Bf[4][2];
    auto ldsA = [&](int bi, int qm) {
#pragma unroll
        for (int f = 0; f < MRH; ++f)
#pragma unroll
            for (int kk = 0; kk < 2; ++kk) {
                int row = wr * (BM / 2) + qm * (BM / 4) + f * 16 + lr;
                int o = row * 128 + kk * 64 + kg * 16;
                o ^= ((o >> 9) & 1) << 5;
                Af[f][kk] = *(const bf16x8*)(smem + bi * TA + o);
            }
    };
    auto ldsB = [&](int bi) {
#pragma unroll
        for (int n = 0; n < 4; ++n)
#pragma unroll
            for (int kk = 0; kk < 2; ++kk) {
                int row = wc * 64 + n * 16 + lr;
                int o = row * 128 + kk * 64 + kg * 16;
                o ^= ((o >> 9) & 1) << 5;
                Bf[n][kk] = *(const bf16x8*)(smem + 2 * TA + bi * TB + o);
            }
    };

    f32x4 acc[MR][4];
#pragma unroll
    for (int m = 0; m < MR; ++m)
#pragma unroll
        for (int n = 0; n < 4; ++n)
#pragma unroll
            for (int i = 0; i < 4; ++i) acc[m][n][i] = 0.f;

    auto mfma16 = [&](int qm, int qn) {
        __builtin_amdgcn_s_setprio(1);
#pragma unroll
        for (int f = 0; f < MRH; ++f)
#pragma unroll
            for (int n2 = 0; n2 < 2; ++n2)
#pragma unroll
                for (int kk = 0; kk < 2; ++kk)
                    acc[qm * MRH + f][qn * 2 + n2] =
                        __builtin_amdgcn_mfma_f32_16x16x32_bf16(
                            Af[f][kk], Bf[qn * 2 + n2][kk],
                            acc[qm * MRH + f][qn * 2 + n2], 0, 0, 0);
        __builtin_amdgcn_s_setprio(0);
    };

    // ---- prologue: tile0 fully; tile1 all but its "late" A chunks ----
    if constexpr (BM == 256) {
        stA(0, 0, 0); stA(0, 1, 0); stA(0, 2, 0); stA(0, 3, 0);
        stB(0, 0, 0); stB(0, 1, 0); stB(0, 2, 0); stB(0, 3, 0);
        stB(1, 0, 1); stB(1, 1, 1); stB(1, 2, 1); stB(1, 3, 1);
        stA(1, 0, 1); stA(1, 2, 1);            // A(t1) c1,c3 staged at P1
    } else {
        stA(0, 0, 0); stA(0, 1, 0);
        stB(0, 0, 0); stB(0, 1, 0); stB(0, 2, 0); stB(0, 3, 0);
        stA(1, 0, 1); stA(1, 1, 1);
        stB(1, 0, 1); stB(1, 1, 1); stB(1, 2, 1); stB(1, 3, 1);
    }
    vm6();             // lands all of tile0 (oldest issues)
    barrier_raw();

    const int nIter = K >> 7;   // K/128, >= 2 for all our shapes
    for (int J = 0; J < nIter; ++J) {
        const bool pf  = (J + 1 < nIter);
        const int  kt1 = 2 * J + 1, kt2 = 2 * J + 2, kt3 = 2 * J + 3;
        // P1: read A(t0,qm0)+B(t0) from buf0; stage A(t1) late chunks (BM=256)
        ldsA(0, 0); ldsB(0);
        if constexpr (BM == 256) { stA(1, 1, kt1); stA(1, 3, kt1); }
        barrier_raw(); lgk0(); mfma16(0, 0); barrier_raw();
        // P2: stage B(t0+2) u0,u1 (B(t0) fully consumed into regs at P1)
        if (pf) { stB(0, 0, kt2); stB(0, 1, kt2); }
        barrier_raw(); lgk0(); mfma16(0, 1); barrier_raw();
        // P3: read A(t0,qm1); stage B(t0+2) u2,u3
        ldsA(0, 1);
        if (pf) { stB(0, 2, kt2); stB(0, 3, kt2); }
        barrier_raw(); lgk0(); mfma16(1, 0); barrier_raw();
        // P4: stage A(t0+2) early chunks; counted wait
        if (pf) {
            if constexpr (BM == 256) { stA(0, 0, kt2); stA(0, 2, kt2); }
            else                     { stA(0, 0, kt2); stA(0, 1, kt2); }
        }
        barrier_raw(); lgk0(); mfma16(1, 1);
        if (pf) vm6(); else vm0();
        barrier_raw();
        // P5: read A(t1,qm0)+B(t1) from buf1; stage A(t0+2) late chunks
        ldsA(1, 0); ldsB(1);
        if constexpr (BM == 256) { if (pf) { stA(0, 1, kt2); stA(0, 3, kt2); } }
        barrier_raw(); lgk0(); mfma16(0, 0); barrier_raw();
        // P6: stage B(t1+2) u0,u1
        if (pf) { stB(1, 0, kt3); stB(1, 1, kt3); }
        barrier_raw(); lgk0(); mfma16(0, 1); barrier_raw();
        // P7: read A(t1,qm1); stage B(t1+2) u2,u3
        ldsA(1, 1);
        if (pf) { stB(1, 2, kt3); stB(1, 3, kt3); }
        barrier_raw(); lgk0(); mfma16(1, 0); barrier_raw();
        // P8: stage A(t1+2) early chunks; counted wait
        if (pf) {
            if constexpr (BM == 256) { stA(1, 0, kt3); stA(1, 2, kt3); }
            else                     { stA(1, 0, kt3); stA(1, 1, kt3); }
        }
        barrier_raw(); lgk0(); mfma16(1, 1);
        if (pf) vm6(); else vm0();
        barrier_raw();
    }

    // epilogue: D row = (lane>>4)*4 + i, col = lane&15 per fragment
#pragma unroll
    for (int mf = 0; mf < MR; ++mf) {
#pragma unroll
        for (int n = 0; n < 4; ++n) {
            int col = bn + wc * 64 + n * 16 + lr;
#pragma unroll
            for (int i = 0; i < 4; ++i) {
                int row = bm + wr * (BM / 2) + mf * 16 + kg * 4 + i;
                float v = acc[mf][n][i];
                if (STORE_BF16)
                    ((ushort*)Cp)[(size_t)row * ldc + col] = f2bf(v);
                else
                    ((float*)Cp)[(size_t)row * ldc + col]  = v;
            }
        }
    }
}

// ---------------------------------------------------------------------------
// Scan (fp32, IM discretization), chunk-parallel: passA -> combine -> passB
__device__ __forceinline__ void linoss_coeffs(const float* A_diag, const float* dt_p,
                                              int p, float& m11, float& m12,
                                              float& m21, float& m22,
                                              float& f1, float& f2) {
    float A  = fmaxf(A_diag[p], 0.f);
    float dt = 1.f / (1.f + expf(-dt_p[p]));
    float S  = 1.f / (1.f + dt * dt * A);
    m11 = S;        m12 = -dt * A * S;
    m21 = dt * S;   m22 = S;
    f1  = dt * S;   f2  = dt * dt * S;
}

__global__ void scan_passA(const float* __restrict__ Bu,
                           const float* __restrict__ A_diag,
                           const float* __restrict__ dt_p,
                           float2* __restrict__ sEnd) {
    int c = blockIdx.x * 256 + threadIdx.x;
    int b = blockIdx.y;
    int j = blockIdx.z;
    float m11, m12, m21, m22, f1, f2;
    linoss_coeffs(A_diag, dt_p, c & 1023, m11, m12, m21, m22, f1, f2);
    const float* bu = Bu + ((size_t)(b * TT + j * LCH)) * C2 + c;
    float z = 0.f, y = 0.f;
#pragma unroll 8
    for (int i = 0; i < LCH; ++i) {
        float u  = bu[(size_t)i * C2];
        float z1 = m11 * z + m12 * y + f1 * u;
        float y1 = m21 * z + m22 * y + f2 * u;
        z = z1; y = y1;
    }
    sEnd[((size_t)j * BB + b) * C2 + c] = make_float2(z, y);
}

__global__ void scan_combine(const float* __restrict__ A_diag,
                             const float* __restrict__ dt_p,
                             const float2* __restrict__ sEnd,
                             float2* __restrict__ sInit) {
    int idx = blockIdx.x * 256 + threadIdx.x;   // 0..8191
    int c = idx & (C2 - 1);
    int b = idx >> 11;
    float m11, m12, m21, m22, f1, f2;
    linoss_coeffs(A_diag, dt_p, c & 1023, m11, m12, m21, m22, f1, f2);
    float e11 = m11, e12 = m12, e21 = m21, e22 = m22;   // M^32 by 5 squarings
#pragma unroll
    for (int s = 0; s < 5; ++s) {
        float n11 = e11 * e11 + e12 * e21;
        float n12 = e11 * e12 + e12 * e22;
        float n21 = e21 * e11 + e22 * e21;
        float n22 = e21 * e12 + e22 * e22;
        e11 = n11; e12 = n12; e21 = n21; e22 = n22;
    }
    float z = 0.f, y = 0.f;
    for (int j = 0; j < NC; ++j) {
        size_t off = ((size_t)j * BB + b) * C2 + c;
        sInit[off] = make_float2(z, y);
        float2 le = sEnd[off];
        float z1 = e11 * z + e12 * y + le.x;
        float y1 = e21 * z + e22 * y + le.y;
        z = z1; y = y1;
    }
}

// passB rescans from correct initial state, emits y as bf16 into YSb
__global__ void scan_passB(const float* __restrict__ Bu,
                           const float* __restrict__ A_diag,
                           const float* __restrict__ dt_p,
                           const float2* __restrict__ sInit,
                           ushort* __restrict__ YSb) {
    int c = blockIdx.x * 256 + threadIdx.x;
    int b = blockIdx.y;
    int j = blockIdx.z;
    float m11, m12, m21, m22, f1, f2;
    linoss_coeffs(A_diag, dt_p, c & 1023, m11, m12, m21, m22, f1, f2);
    float2 s0 = sInit[((size_t)j * BB + b) * C2 + c];
    float z = s0.x, y = s0.y;
    const float* bu = Bu  + ((size_t)(b * TT + j * LCH)) * C2 + c;
    ushort*      ys = YSb + ((size_t)(b * TT + j * LCH)) * C2 + c;
#pragma unroll 8
    for (int i = 0; i < LCH; ++i) {
        float u  = bu[(size_t)i * C2];
        float z1 = m11 * z + m12 * y + f1 * u;
        float y1 = m21 * z + m22 * y + f2 * u;
        z = z1; y = y1;
        ys[(size_t)i * C2] = f2bf(y);
    }
}

// ---------------------------------------------------------------------------
// Fused epilogue: o = O + D*x ; rms-normalize ; * nw * swish(g) -> V (bf16)
__global__ void rmsgate_kernel(const float* __restrict__ O,
                               const ushort* __restrict__ XGb,
                               const float* __restrict__ Dv,
                               const float* __restrict__ nw,
                               ushort* __restrict__ V) {
    int m = blockIdx.x;
    int t = threadIdx.x;
    float4  o4 = ((const float4*)(O + (size_t)m * HH))[t];
    ushort4 x4 = ((const ushort4*)(XGb + (size_t)m * C2))[t];
    float4  d4 = ((const float4*)Dv)[t];
    float of[4];
    of[0] = o4.x + d4.x * bf2f(x4.x);
    of[1] = o4.y + d4.y * bf2f(x4.y);
    of[2] = o4.z + d4.z * bf2f(x4.z);
    of[3] = o4.w + d4.w * bf2f(x4.w);
    float ss = of[0]*of[0] + of[1]*of[1] + of[2]*of[2] + of[3]*of[3];
#pragma unroll
    for (int o = 32; o > 0; o >>= 1) ss += __shfl_down(ss, o);
    __shared__ float wsum[4];
    if ((t & 63) == 0) wsum[t >> 6] = ss;
    __syncthreads();
    float tot = wsum[0] + wsum[1] + wsum[2] + wsum[3];
    float r = rsqrtf(tot * (1.f / (float)HH) + 1e-5f);

    ushort4 g4 = ((const ushort4*)(XGb + (size_t)m * C2 + HH))[t];
    float4  w4 = ((const float4*)nw)[t];
    float g[4] = {bf2f(g4.x), bf2f(g4.y), bf2f(g4.z), bf2f(g4.w)};
    float w[4] = {w4.x, w4.y, w4.z, w4.w};
    ushort4 vout;
    ushort* vo = &vout.x;
#pragma unroll
    for (int i = 0; i < 4; ++i) {
        float sw = g[i] / (1.f + expf(-g[i]));
        vo[i] = f2bf(of[i] * r * w[i] * sw);
    }
    ((ushort4*)(V + (size_t)m * HH))[t] = vout;
}

// ---------------------------------------------------------------------------
extern "C" void kernel_launch(void* const* d_in, const int* in_sizes, int n_in,
                              void* d_out, int out_size, void* d_ws, size_t ws_size,
                              hipStream_t stream) {
    const float* hs      = (const float*)d_in[0];
    const float* Wi      = (const float*)d_in[1];
    const float* Wg      = (const float*)d_in[2];
    const float* Wo      = (const float*)d_in[3];
    const float* A_diag  = (const float*)d_in[4];
    const float* B_param = (const float*)d_in[5];
    const float* C_param = (const float*)d_in[6];
    const float* Dv      = (const float*)d_in[7];
    const float* dtp     = (const float*)d_in[8];
    const float* nw      = (const float*)d_in[9];
    float* out = (float*)d_out;

    char* ws = (char*)d_ws;
    ushort* hsb  = (ushort*)ws;                                   ws += (size_t)MT * HH * 2;   // 16 MB
    ushort* Wigb = (ushort*)ws;                                   ws += (size_t)C2 * HH * 2;   //  4 MB
    ushort* Wob  = (ushort*)ws;                                   ws += (size_t)HH * HH * 2;   //  2 MB
    ushort* Bpkb = (ushort*)ws;                                   ws += (size_t)C2 * HH * 2;   //  4 MB
    ushort* Cpkb = (ushort*)ws;                                   ws += (size_t)HH * C2 * 2;   //  4 MB
    ushort* XGb  = (ushort*)ws;                                   ws += (size_t)MT * C2 * 2;   // 32 MB
    float*  Bu   = (float*)ws;                                    ws += (size_t)MT * C2 * 4;   // 64 MB
    ushort* YSb  = (ushort*)ws;                                   ws += (size_t)MT * C2 * 2;   // 32 MB
    float*  O    = (float*)ws;                                    ws += (size_t)MT * HH * 4;   // 32 MB
    ushort* Vb   = (ushort*)ws;                                   ws += (size_t)MT * HH * 2;   // 16 MB
    float2* sEnd  = (float2*)ws;                                  ws += (size_t)NC * BB * C2 * 8;
    float2* sInit = (float2*)ws;

    dim3 blk(256);

    // convert / repack params and activations to bf16
    f32_to_bf16_k<<<dim3((MT * HH) / 1024), blk, 0, stream>>>(hs, hsb);
    f32_to_bf16_k<<<dim3((HH * HH) / 1024), blk, 0, stream>>>(Wi, Wigb);
    f32_to_bf16_k<<<dim3((HH * HH) / 1024), blk, 0, stream>>>(Wg, Wigb + (size_t)HH * HH);
    f32_to_bf16_k<<<dim3((HH * HH) / 1024), blk, 0, stream>>>(Wo, Wob);
    repack_B_bf<<<dim3((PP * HH) / 256), blk, 0, stream>>>(B_param, Bpkb);
    repack_C_bf<<<dim3((HH * PP) / 256), blk, 0, stream>>>(C_param, Cpkb);

    // XG = hs @ [Wi|Wg]^T   (M=8192, N=2048, K=1024) -> bf16, grid 8x32=256
    gemm8p<256, 1><<<dim3(256), dim3(512), 0, stream>>>(
        hsb, HH, Wigb, HH, XGb, C2, HH, 8);

    // Bu = x @ Bpk^T        (M=8192, N=2048, K=1024) -> fp32
    gemm8p<256, 0><<<dim3(256), dim3(512), 0, stream>>>(
        XGb, C2, Bpkb, HH, Bu, C2, HH, 8);

    // chunked linear scan (fp32), YS emitted as bf16
    scan_passA<<<dim3(C2 / 256, BB, NC), blk, 0, stream>>>(Bu, A_diag, dtp, sEnd);
    scan_combine<<<dim3((BB * C2) / 256), blk, 0, stream>>>(A_diag, dtp, sEnd, sInit);
    scan_passB<<<dim3(C2 / 256, BB, NC), blk, 0, stream>>>(Bu, A_diag, dtp, sInit, YSb);

    // O = YS @ Cpk^T        (M=8192, N=1024, K=2048) -> fp32, grid 4x64=256
    gemm8p<128, 0><<<dim3(256), dim3(512), 0, stream>>>(
        YSb, C2, Cpkb, C2, O, HH, C2, 4);

    // fused D*x + RMSNorm + swish gate -> V (bf16)
    rmsgate_kernel<<<dim3(MT), blk, 0, stream>>>(O, XGb, Dv, nw, Vb);

    // out = V @ Wo^T        (M=8192, N=1024, K=1024) -> fp32
    gemm8p<128, 0><<<dim3(256), dim3(512), 0, stream>>>(
        Vb, HH, Wob, HH, out, HH, HH, 4);
}